// Round 2
// baseline (481.936 us; speedup 1.0000x reference)
//
#include <hip/hip_runtime.h>

// UIFeatureEmbedding: 8-table gather + concat + per-head Linear (48 -> 64), fp32.
// B=16384, user heads 0-3 from tables 0-3, item heads 4-7 from tables 4-7.
// Table dims: {64,64,32,32} per side; concat = 192 per side = 4 heads * 48.
//
// Decomposition: one 64-thread block (1 wave) = (sample_group of 64, head, d_half).
//   lane = sample within group. e-segment (48 floats) gathered into 12 float4 VGPRs.
//   head/d_half derive from blockIdx => wave-uniform => weight reads become s_load
//   (scalar pipe), leaving VALU purely for the 1536 FMAs/lane. No LDS at all.
// Grid 4096 = 256 groups * 16 jobs; blockIdx = job*256 + group keeps all 16 jobs
//   of a group on the same XCD (round-robin dispatch) for gather L2 locality.

#define BATCH   16384
#define NHEADS  8
#define HD      64
#define SPLIT   48
#define DQ      2           // d-split: 2 jobs of 32 d-values per (group, head)
#define DPJ     (HD / DQ)   // 32

__global__ __launch_bounds__(64, 4)
void ui_emb_kernel(const int* __restrict__ f0, const int* __restrict__ f1,
                   const int* __restrict__ f2, const int* __restrict__ f3,
                   const int* __restrict__ f4, const int* __restrict__ f5,
                   const int* __restrict__ f6, const int* __restrict__ f7,
                   const float* __restrict__ e0, const float* __restrict__ e1,
                   const float* __restrict__ e2, const float* __restrict__ e3,
                   const float* __restrict__ e4, const float* __restrict__ e5,
                   const float* __restrict__ e6, const float* __restrict__ e7,
                   const float* __restrict__ Wu, const float* __restrict__ Wi,
                   float* __restrict__ out)
{
    const int lane  = threadIdx.x;        // 0..63 = sample within group
    const int bid   = blockIdx.x;         // 0..4095
    const int group = bid & 255;          // 256 sample-groups; same-XCD for a group's jobs
    const int job   = bid >> 8;           // 0..15
    const int head  = job >> 1;           // 0..7 (global head)
    const int dq    = job & 1;            // which 32-wide d-half

    const int  b    = group * 64 + lane;  // sample id
    const bool user = (head < 4);
    const int  hn   = user ? head : head - 4;   // head within side, 0..3

    // ---- table geometry for this head's 48-float segment of the 192 concat ----
    // side layout: [t0:64 | t1:64 | t2:32 | t3:32]
    const int p0 = hn * SPLIT;                 // 0,48,96,144
    const int pL = p0 + SPLIT - 4;             // last chunk position
    auto tbl = [](int p) { return p < 64 ? 0 : p < 128 ? 1 : p < 160 ? 2 : 3; };
    const int tA = tbl(p0);
    const int tB = tbl(pL);                    // tA or tA+1

    // uniform pointer selects (head is wave-uniform)
    const int* fA;
    const int* fB;
    const float* ebA;
    const float* ebB;
    if (user) {
        fA  = tA == 0 ? f0 : tA == 1 ? f1 : tA == 2 ? f2 : f3;
        fB  = tB == 0 ? f0 : tB == 1 ? f1 : tB == 2 ? f2 : f3;
        ebA = tA == 0 ? e0 : tA == 1 ? e1 : tA == 2 ? e2 : e3;
        ebB = tB == 0 ? e0 : tB == 1 ? e1 : tB == 2 ? e2 : e3;
    } else {
        fA  = tA == 0 ? f4 : tA == 1 ? f5 : tA == 2 ? f6 : f7;
        fB  = tB == 0 ? f4 : tB == 1 ? f5 : tB == 2 ? f6 : f7;
        ebA = tA == 0 ? e4 : tA == 1 ? e5 : tA == 2 ? e6 : e7;
        ebB = tB == 0 ? e4 : tB == 1 ? e5 : tB == 2 ? e6 : e7;
    }
    const int dimA = tA < 2 ? 64 : 32;
    const int dimB = tB < 2 ? 64 : 32;

    // per-lane row pointers (coalesced int loads of the indices)
    const int idxA = fA[b];
    const int idxB = fB[b];
    const float* rowA = ebA + (size_t)idxA * dimA;
    const float* rowB = ebB + (size_t)idxB * dimB;

    // ---- gather the 48-float e-segment into registers (12 x float4) ----
    float4 ev[12];
#pragma unroll
    for (int c = 0; c < 12; ++c) {
        const int p  = p0 + c * 4;                                  // uniform
        const int t  = p < 64 ? 0 : p < 128 ? 1 : p < 160 ? 2 : 3;  // uniform
        const int ob = t == 0 ? 0 : t == 1 ? 64 : t == 2 ? 128 : 160;
        const float* row = (t == tA) ? rowA : rowB;                 // per-lane select
        ev[c] = *reinterpret_cast<const float4*>(row + (p - ob));
    }

    // ---- per-head Linear: acc[d] = sum_s ev[s] * W[head][d][s] ----
    // W layout (Linear): [4][64][48], row-major. Uniform address => s_load.
    const float* W = (user ? Wu : Wi) + ((size_t)hn * HD + dq * DPJ) * SPLIT;

    float* op = out + ((size_t)b * NHEADS + head) * HD + dq * DPJ;

#pragma unroll
    for (int dg = 0; dg < DPJ / 4; ++dg) {      // 8 groups of 4 outputs
        float a0 = 0.f, a1 = 0.f, a2 = 0.f, a3 = 0.f;
        const float* Wd = W + dg * 4 * SPLIT;
#pragma unroll
        for (int c = 0; c < 12; ++c) {
            const float4 v = ev[c];
            const float* w0 = Wd + 0 * SPLIT + c * 4;
            const float* w1 = Wd + 1 * SPLIT + c * 4;
            const float* w2 = Wd + 2 * SPLIT + c * 4;
            const float* w3 = Wd + 3 * SPLIT + c * 4;
            a0 = fmaf(v.x, w0[0], a0); a0 = fmaf(v.y, w0[1], a0);
            a0 = fmaf(v.z, w0[2], a0); a0 = fmaf(v.w, w0[3], a0);
            a1 = fmaf(v.x, w1[0], a1); a1 = fmaf(v.y, w1[1], a1);
            a1 = fmaf(v.z, w1[2], a1); a1 = fmaf(v.w, w1[3], a1);
            a2 = fmaf(v.x, w2[0], a2); a2 = fmaf(v.y, w2[1], a2);
            a2 = fmaf(v.z, w2[2], a2); a2 = fmaf(v.w, w2[3], a2);
            a3 = fmaf(v.x, w3[0], a3); a3 = fmaf(v.y, w3[1], a3);
            a3 = fmaf(v.z, w3[2], a3); a3 = fmaf(v.w, w3[3], a3);
        }
        float4 o; o.x = a0; o.y = a1; o.z = a2; o.w = a3;
        *reinterpret_cast<float4*>(op + dg * 4) = o;
    }
}

extern "C" void kernel_launch(void* const* d_in, const int* in_sizes, int n_in,
                              void* d_out, int out_size, void* d_ws, size_t ws_size,
                              hipStream_t stream)
{
    const int*   f0 = (const int*)d_in[0];
    const int*   f1 = (const int*)d_in[1];
    const int*   f2 = (const int*)d_in[2];
    const int*   f3 = (const int*)d_in[3];
    const int*   f4 = (const int*)d_in[4];
    const int*   f5 = (const int*)d_in[5];
    const int*   f6 = (const int*)d_in[6];
    const int*   f7 = (const int*)d_in[7];
    const float* e0 = (const float*)d_in[8];
    const float* e1 = (const float*)d_in[9];
    const float* e2 = (const float*)d_in[10];
    const float* e3 = (const float*)d_in[11];
    const float* e4 = (const float*)d_in[12];
    const float* e5 = (const float*)d_in[13];
    const float* e6 = (const float*)d_in[14];
    const float* e7 = (const float*)d_in[15];
    const float* Wu = (const float*)d_in[16];
    const float* Wi = (const float*)d_in[17];
    float* out = (float*)d_out;

    // grid = 256 sample-groups * 16 jobs (8 heads * 2 d-halves)
    const int grid = (BATCH / 64) * NHEADS * DQ;   // 4096
    ui_emb_kernel<<<grid, 64, 0, stream>>>(f0, f1, f2, f3, f4, f5, f6, f7,
                                           e0, e1, e2, e3, e4, e5, e6, e7,
                                           Wu, Wi, out);
}